// Round 2
// baseline (2678.003 us; speedup 1.0000x reference)
//
#include <hip/hip_runtime.h>
#include <math.h>

// SequentialVAE on MI355X.
//  K1  gemm: h = relu(X@W1+b1)
//  K2  gemms: mu, Aout=h@WA+bA, Qtop=h@WB[:1024], Qbot=h@WB[1024:]
//  K3  per-t: AA_t = A A^T + B_{t-1}B_{t-1}^T + 1e-6 I ; BB_t = B_t A_t^T ; zero logdet
//  K4  chunked Riccati, cold-start seed D = A A^T + 1e-6 I (closed-form; exact at t=0),
//      W=256 warmup: D_{t+1} = AA_{t+1} - BB_t D_t^{-1} BB_t^T
//  K5  per-t (parallel): L_t = chol(D_t), Linv_t = L_t^{-1}, C_t = BB_t Linv_t^T
//  K6  per-chunk sequential x with 384-step cold-start warmup (x=0):
//      x_t = Linv_t (I - C_{t-1} x_{t-1}); emit r=max(x,1e-5), logdet, sample_z
//  K7  entropy = logdet + DX*T/2*(1+log(2pi))

#define T_STEPS 8192
#define DXX 1024

// ---------------- generic fp32 GEMM: out = act(A[MxK] @ W[KxN] + bias) ----------------
#define BM 64
#define BN 64
#define BKK 16

__global__ __launch_bounds__(256) void gemm_bias_act(
    const float* __restrict__ A, const float* __restrict__ W,
    const float* __restrict__ bias, float* __restrict__ out,
    int M, int N, int K, int do_relu)
{
  __shared__ float As[BKK][BM + 4];
  __shared__ float Bs[BKK][BN];
  int tid = threadIdx.x;
  int bm = blockIdx.y * BM;
  int bn = blockIdx.x * BN;
  int ty = tid >> 4;
  int tx = tid & 15;
  float acc[4][4] = {};
  int lr = tid >> 2;
  int lc = (tid & 3) << 2;
  int br = tid >> 4;
  int bc = (tid & 15) << 2;
  for (int k0 = 0; k0 < K; k0 += BKK) {
    float4 av = *(const float4*)(A + (size_t)(bm + lr) * K + k0 + lc);
    float4 wv;
    int cb = bn + bc;
    const float* wrow = W + (size_t)(k0 + br) * N;
    if (cb + 3 < N) {
      wv = *(const float4*)(wrow + cb);
    } else {
      wv.x = (cb + 0 < N) ? wrow[cb + 0] : 0.f;
      wv.y = (cb + 1 < N) ? wrow[cb + 1] : 0.f;
      wv.z = (cb + 2 < N) ? wrow[cb + 2] : 0.f;
      wv.w = (cb + 3 < N) ? wrow[cb + 3] : 0.f;
    }
    __syncthreads();
    As[lc + 0][lr] = av.x;
    As[lc + 1][lr] = av.y;
    As[lc + 2][lr] = av.z;
    As[lc + 3][lr] = av.w;
    *(float4*)&Bs[br][bc] = wv;
    __syncthreads();
#pragma unroll
    for (int kk = 0; kk < BKK; ++kk) {
      float4 a4 = *(const float4*)&As[kk][ty * 4];
      float4 b4 = *(const float4*)&Bs[kk][tx * 4];
      float a[4] = {a4.x, a4.y, a4.z, a4.w};
      float b[4] = {b4.x, b4.y, b4.z, b4.w};
#pragma unroll
      for (int i = 0; i < 4; ++i)
#pragma unroll
        for (int j = 0; j < 4; ++j) acc[i][j] = fmaf(a[i], b[j], acc[i][j]);
    }
  }
#pragma unroll
  for (int i = 0; i < 4; ++i) {
    int row = bm + ty * 4 + i;
#pragma unroll
    for (int j = 0; j < 4; ++j) {
      int col = bn + tx * 4 + j;
      if (col < N) {
        float v = acc[i][j] + (bias ? bias[col] : 0.f);
        if (do_relu) v = fmaxf(v, 0.f);
        out[(size_t)row * N + col] = v;
      }
    }
  }
}

// ---------------- K3: AA_t, BB_t ----------------
__global__ __launch_bounds__(256) void make_psd(
    const float* __restrict__ Aout, const float* __restrict__ Qtop,
    const float* __restrict__ Qbot, const float* __restrict__ bB,
    float* __restrict__ AA, float* __restrict__ BBm, float* __restrict__ logdet)
{
  int t = blockIdx.x;
  int tid = threadIdx.x;
  int i = tid >> 4, j = tid & 15;
  if (t == 0 && tid == 0) *logdet = 0.f;
  __shared__ float a[16][17], bp[16][17], bq[16][17];
  a[i][j] = Aout[(size_t)t * 256 + tid] + (i == j ? 1.f : 0.f);
  bp[i][j] = (t >= 1) ? (Qtop[(size_t)t * 256 + tid] + Qbot[(size_t)(t - 1) * 256 + tid] + bB[tid]) : 0.f;
  bool has_b = (t < T_STEPS - 1);
  if (has_b) bq[i][j] = Qtop[(size_t)(t + 1) * 256 + tid] + Qbot[(size_t)t * 256 + tid] + bB[tid];
  __syncthreads();
  float s = (i == j) ? 1e-6f : 0.f;
#pragma unroll
  for (int k = 0; k < 16; ++k) s += a[i][k] * a[j][k] + bp[i][k] * bp[j][k];
  AA[(size_t)t * 256 + tid] = s;
  if (has_b) {
    float s2 = 0.f;
#pragma unroll
    for (int k = 0; k < 16; ++k) s2 += bq[i][k] * a[j][k];
    BBm[(size_t)t * 256 + tid] = s2;
  }
}

// ---------------- K4: chunked Riccati, closed-form seed D = A A^T + eps I ----------------
#define RIC_S 64
#define RIC_W 256
#define RIC_NCH (T_STEPS / RIC_S)   // 128

__global__ __launch_bounds__(256) void riccati_chunk(
    const float* __restrict__ AA, const float* __restrict__ BBm,
    const float* __restrict__ Aout, float* __restrict__ D)
{
  int p = blockIdx.x;
  int tid = threadIdx.x;
  int i = tid >> 4, j = tid & 15;
  int t0 = p * RIC_S;
  int tw = t0 - RIC_W; if (tw < 0) tw = 0;
  int tend = t0 + RIC_S - 1;
  __shared__ float d[16][17], y[16][17], bb[16][17], aa[16][17];
  // closed-form seed: D ~= A A^T + eps I (EXACT at t=0 since offd_sq[0]=0)
  aa[i][j] = Aout[(size_t)tw * 256 + tid] + (i == j ? 1.f : 0.f);
  __syncthreads();
  {
    float s = (i == j) ? 1e-6f : 0.f;
#pragma unroll
    for (int k = 0; k < 16; ++k) s += aa[i][k] * aa[j][k];
    d[i][j] = s;
  }
  for (int t = tw; ; ++t) {
    __syncthreads();
    if (t >= t0) D[(size_t)t * 256 + tid] = d[i][j];
    if (t == tend) break;
    bb[i][j] = BBm[(size_t)t * 256 + tid];
    aa[i][j] = AA[(size_t)(t + 1) * 256 + tid];
    // in-place Gauss-Jordan inverse of SPD d
    for (int k = 0; k < 16; ++k) {
      __syncthreads();
      float pv = d[k][k];
      float rowv = d[k][j];
      float colv = d[i][k];
      float self = d[i][j];
      __syncthreads();
      float nv;
      if (i == k && j == k)      nv = 1.f / pv;
      else if (i == k)           nv = rowv / pv;
      else if (j == k)           nv = -colv / pv;
      else                       nv = self - colv * rowv / pv;
      d[i][j] = nv;
    }
    __syncthreads();
    float s = 0.f;
#pragma unroll
    for (int k = 0; k < 16; ++k) s += d[i][k] * bb[j][k];   // y = Dinv BB^T
    y[i][j] = s;
    __syncthreads();
    float s2 = aa[i][j];
#pragma unroll
    for (int k = 0; k < 16; ++k) s2 -= bb[i][k] * y[k][j];  // AA - BB y
    __syncthreads();
    d[i][j] = s2;
  }
}

// ---------------- K5: per-t chol, Linv, C (fully parallel) ----------------
__global__ __launch_bounds__(256) void chol_inv(
    const float* __restrict__ D, const float* __restrict__ BBm,
    float* __restrict__ Linv, float* __restrict__ Cmat)
{
  int t = blockIdx.x;
  int tid = threadIdx.x;
  int i = tid >> 4, j = tid & 15;
  __shared__ float d[16][17], li[16][17], rhs[16][17], bb[16][17];
  d[i][j] = D[(size_t)t * 256 + tid];
  bool has_b = (t < T_STEPS - 1);
  if (has_b) bb[i][j] = BBm[(size_t)t * 256 + tid];
  rhs[i][j] = (i == j) ? 1.f : 0.f;
  __syncthreads();
  for (int k = 0; k < 16; ++k) {
    if (tid == k * 16 + k) d[k][k] = sqrtf(d[k][k]);
    __syncthreads();
    if (j == k && i > k) d[i][k] /= d[k][k];
    __syncthreads();
    if (i > k && j > k && j <= i) d[i][j] -= d[i][k] * d[j][k];
    __syncthreads();
  }
  for (int k = 0; k < 16; ++k) {
    if (i == k) li[k][j] = rhs[k][j] / d[k][k];
    __syncthreads();
    if (i > k) rhs[i][j] -= d[i][k] * li[k][j];
    __syncthreads();
  }
  Linv[(size_t)t * 256 + tid] = li[i][j];
  if (has_b) {
    float s = 0.f;
#pragma unroll
    for (int k = 0; k < 16; ++k) s += bb[i][k] * li[j][k];   // C = BB Linv^T
    Cmat[(size_t)t * 256 + tid] = s;
  }
}

// ---------------- K6: per-chunk sequential x with warmup + epilogue ----------------
#define XS 64
#define XW 384
#define XNCH (T_STEPS / XS)   // 128

__global__ __launch_bounds__(256) void xseq(
    const float* __restrict__ Linv, const float* __restrict__ Cmat,
    const float* __restrict__ mu, const float* __restrict__ eps,
    float* __restrict__ out, float* __restrict__ logdet)
{
  int p = blockIdx.x;
  int tid = threadIdx.x;
  int i = tid >> 4, j = tid & 15;
  int t0 = p * XS;
  int tstart = t0 - XW; if (tstart < 0) tstart = 0;  // tstart==0 path is EXACT (x_{-1} nonexistent)
  __shared__ float li[16][17], c[16][17], tmp[16][17], x[16][17], r[16][17], ev[16];
  __shared__ float red[256];
  float logacc = 0.f;
  x[i][j] = 0.f;
  for (int t = tstart; t < t0 + XS; ++t) {
    bool emit = (t >= t0);
    __syncthreads();                       // A: prev iteration fully done (incl. sz reads)
    li[i][j] = Linv[(size_t)t * 256 + tid];
    if (t > 0) c[i][j] = Cmat[(size_t)(t - 1) * 256 + tid];
    if (emit && tid < 16) ev[tid] = eps[(size_t)t * 16 + tid];
    __syncthreads();                       // B: loads visible
    float tm = (i == j) ? 1.f : 0.f;
    if (t > 0) {
#pragma unroll
      for (int k = 0; k < 16; ++k) tm -= c[i][k] * x[k][j];   // I - C x
    }
    tmp[i][j] = tm;
    __syncthreads();                       // C: tmp visible; x reads done
    float xn = 0.f;
#pragma unroll
    for (int k = 0; k < 16; ++k) xn += li[i][k] * tmp[k][j];  // x = Linv (I - C x)
    x[i][j] = xn;
    if (emit) {
      float rv = fmaxf(xn, 1e-5f);
      r[i][j] = rv;
      if (i == j) logacc -= logf(rv);
    }
    __syncthreads();                       // D: x, r visible
    if (emit && i == 0) {
      float sz = mu[(size_t)t * 16 + j];
#pragma unroll
      for (int k = 0; k < 16; ++k) sz = fmaf(r[k][j], ev[k], sz);  // mu + r^T eps
      out[1 + (size_t)t * 16 + j] = sz;
    }
  }
  red[tid] = logacc;
  __syncthreads();
  for (int off = 128; off > 0; off >>= 1) {
    if (tid < off) red[tid] += red[tid + off];
    __syncthreads();
  }
  if (tid == 0) atomicAdd(logdet, red[0]);
}

// ---------------- K7: entropy ----------------
__global__ void finalize_entropy(const float* __restrict__ logdet, float* __restrict__ out)
{
  if (threadIdx.x == 0 && blockIdx.x == 0) {
    const double ENT = 0.5 * 1024.0 * 8192.0 * (1.0 + 1.8378770664093454);
    out[0] = (float)(ENT + (double)(*logdet));
  }
}

extern "C" void kernel_launch(void* const* d_in, const int* in_sizes, int n_in,
                              void* d_out, int out_size, void* d_ws, size_t ws_size,
                              hipStream_t stream)
{
  const float* X   = (const float*)d_in[0];
  const float* W1  = (const float*)d_in[1];
  const float* b1  = (const float*)d_in[2];
  const float* Wmu = (const float*)d_in[3];
  const float* bmu = (const float*)d_in[4];
  const float* WA  = (const float*)d_in[5];
  const float* bA  = (const float*)d_in[6];
  const float* WB  = (const float*)d_in[7];
  const float* bB  = (const float*)d_in[8];
  const float* eps = (const float*)d_in[9];
  float* out = (float*)d_out;
  float* ws  = (float*)d_ws;

  // workspace layout (floats), region reuse once producers are dead:
  // [0 .. 8388608)           h      (dead after K2) -> AA@0, BB@2097152, logdet@4194304
  // [8388608 .. 8519680)     mu
  // [8519680 .. 10616832)    Aout   (alive through K4 seed) -> Cmat (K5 output)
  // [10616832 .. 12713984)   Qtop   (dead after K3) -> D
  // [12713984 .. 14811136)   Qbot   (dead after K3) -> Linv
  float* h      = ws;
  float* AAp    = ws;
  float* BBp    = ws + 2097152;
  float* logdet = ws + 4194304;
  float* muw    = ws + 8388608;
  float* Aout   = ws + 8519680;  float* Cmat = Aout;
  float* Qtop   = ws + 10616832; float* Dws  = Qtop;
  float* Qbot   = ws + 12713984; float* Linv = Qbot;

  dim3 blk(256);

  gemm_bias_act<<<dim3(DXX / BN, T_STEPS / BM), blk, 0, stream>>>(X, W1, b1, h, T_STEPS, DXX, DXX, 1);
  gemm_bias_act<<<dim3(1, T_STEPS / BM), blk, 0, stream>>>(h, Wmu, bmu, muw, T_STEPS, 16, DXX, 0);
  gemm_bias_act<<<dim3(256 / BN, T_STEPS / BM), blk, 0, stream>>>(h, WA, bA, Aout, T_STEPS, 256, DXX, 0);
  gemm_bias_act<<<dim3(256 / BN, T_STEPS / BM), blk, 0, stream>>>(h, WB, nullptr, Qtop, T_STEPS, 256, DXX, 0);
  gemm_bias_act<<<dim3(256 / BN, T_STEPS / BM), blk, 0, stream>>>(h, WB + 1024 * 256, nullptr, Qbot, T_STEPS, 256, DXX, 0);
  make_psd<<<dim3(T_STEPS), blk, 0, stream>>>(Aout, Qtop, Qbot, bB, AAp, BBp, logdet);
  riccati_chunk<<<dim3(RIC_NCH), blk, 0, stream>>>(AAp, BBp, Aout, Dws);
  chol_inv<<<dim3(T_STEPS), blk, 0, stream>>>(Dws, BBp, Linv, Cmat);
  xseq<<<dim3(XNCH), blk, 0, stream>>>(Linv, Cmat, muw, eps, out, logdet);
  finalize_entropy<<<dim3(1), dim3(64), 0, stream>>>(logdet, out);
}

// Round 3
// 1394.634 us; speedup vs baseline: 1.9202x; 1.9202x over previous
//
#include <hip/hip_runtime.h>
#include <math.h>

// SequentialVAE on MI355X.
//  K1  gemm: h = relu(X@W1+b1)
//  K2  gemms: mu, Aout=h@WA+bA, Qtop=h@WB[:1024], Qbot=h@WB[1024:]
//  K3  per-t: AA_t = A A^T + B_{t-1}B_{t-1}^T + 1e-6 I ; BB_t = B_t A_t^T ; zero logdet
//  K4  riccati_wave: 1 wave/chunk, 256 chunks x 32 steps, W=192 warmup,
//      seed D = (Aout+I)(Aout+I)^T + 1e-6 I (exact at t=0). GJ inverse in registers
//      via shuffles; matmuls via LDS stride-20 rows. Single-wave WG => barriers ~free.
//  K5  per-t (parallel): L_t = chol(D_t), Linv_t = L_t^{-1}, C_t = BB_t Linv_t^T
//  K6  xseq_wave: 1 wave/chunk, 256 chunks x 32 steps, 192-step warmup (x=0):
//      x_t = Linv_t (I - C_{t-1} x_{t-1}); r=max(x,1e-5); logdet; sample_z
//  K7  entropy = logdet + DX*T/2*(1+log(2pi))

#define T_STEPS 8192
#define DXX 1024

#define DOT4(r, b) ((r).x*(b).x + (r).y*(b).y + (r).z*(b).z + (r).w*(b).w)

// ---------------- generic fp32 GEMM: out = act(A[MxK] @ W[KxN] + bias) ----------------
#define BM 64
#define BN 64
#define BKK 16

__global__ __launch_bounds__(256) void gemm_bias_act(
    const float* __restrict__ A, const float* __restrict__ W,
    const float* __restrict__ bias, float* __restrict__ out,
    int M, int N, int K, int do_relu)
{
  __shared__ float As[BKK][BM + 4];
  __shared__ float Bs[BKK][BN];
  int tid = threadIdx.x;
  int bm = blockIdx.y * BM;
  int bn = blockIdx.x * BN;
  int ty = tid >> 4;
  int tx = tid & 15;
  float acc[4][4] = {};
  int lr = tid >> 2;
  int lc = (tid & 3) << 2;
  int br = tid >> 4;
  int bc = (tid & 15) << 2;
  for (int k0 = 0; k0 < K; k0 += BKK) {
    float4 av = *(const float4*)(A + (size_t)(bm + lr) * K + k0 + lc);
    float4 wv;
    int cb = bn + bc;
    const float* wrow = W + (size_t)(k0 + br) * N;
    if (cb + 3 < N) {
      wv = *(const float4*)(wrow + cb);
    } else {
      wv.x = (cb + 0 < N) ? wrow[cb + 0] : 0.f;
      wv.y = (cb + 1 < N) ? wrow[cb + 1] : 0.f;
      wv.z = (cb + 2 < N) ? wrow[cb + 2] : 0.f;
      wv.w = (cb + 3 < N) ? wrow[cb + 3] : 0.f;
    }
    __syncthreads();
    As[lc + 0][lr] = av.x;
    As[lc + 1][lr] = av.y;
    As[lc + 2][lr] = av.z;
    As[lc + 3][lr] = av.w;
    *(float4*)&Bs[br][bc] = wv;
    __syncthreads();
#pragma unroll
    for (int kk = 0; kk < BKK; ++kk) {
      float4 a4 = *(const float4*)&As[kk][ty * 4];
      float4 b4 = *(const float4*)&Bs[kk][tx * 4];
      float a[4] = {a4.x, a4.y, a4.z, a4.w};
      float b[4] = {b4.x, b4.y, b4.z, b4.w};
#pragma unroll
      for (int i = 0; i < 4; ++i)
#pragma unroll
        for (int j = 0; j < 4; ++j) acc[i][j] = fmaf(a[i], b[j], acc[i][j]);
    }
  }
#pragma unroll
  for (int i = 0; i < 4; ++i) {
    int row = bm + ty * 4 + i;
#pragma unroll
    for (int j = 0; j < 4; ++j) {
      int col = bn + tx * 4 + j;
      if (col < N) {
        float v = acc[i][j] + (bias ? bias[col] : 0.f);
        if (do_relu) v = fmaxf(v, 0.f);
        out[(size_t)row * N + col] = v;
      }
    }
  }
}

// ---------------- K3: AA_t, BB_t ----------------
__global__ __launch_bounds__(256) void make_psd(
    const float* __restrict__ Aout, const float* __restrict__ Qtop,
    const float* __restrict__ Qbot, const float* __restrict__ bB,
    float* __restrict__ AA, float* __restrict__ BBm, float* __restrict__ logdet)
{
  int t = blockIdx.x;
  int tid = threadIdx.x;
  int i = tid >> 4, j = tid & 15;
  if (t == 0 && tid == 0) *logdet = 0.f;
  __shared__ float a[16][17], bp[16][17], bq[16][17];
  a[i][j] = Aout[(size_t)t * 256 + tid] + (i == j ? 1.f : 0.f);
  bp[i][j] = (t >= 1) ? (Qtop[(size_t)t * 256 + tid] + Qbot[(size_t)(t - 1) * 256 + tid] + bB[tid]) : 0.f;
  bool has_b = (t < T_STEPS - 1);
  if (has_b) bq[i][j] = Qtop[(size_t)(t + 1) * 256 + tid] + Qbot[(size_t)t * 256 + tid] + bB[tid];
  __syncthreads();
  float s = (i == j) ? 1e-6f : 0.f;
#pragma unroll
  for (int k = 0; k < 16; ++k) s += a[i][k] * a[j][k] + bp[i][k] * bp[j][k];
  AA[(size_t)t * 256 + tid] = s;
  if (has_b) {
    float s2 = 0.f;
#pragma unroll
    for (int k = 0; k < 16; ++k) s2 += bq[i][k] * a[j][k];
    BBm[(size_t)t * 256 + tid] = s2;
  }
}

// ---------------- K4: wave-level chunked Riccati ----------------
// Layout: lane l = q*16+c (q=l>>4, c=l&15) holds d[4q+u][c], u=0..3 in dr[u].
#define RIC_S 32
#define RIC_W 192
#define RIC_NCH (T_STEPS / RIC_S)   // 256

__global__ __launch_bounds__(64) void riccati_wave(
    const float* __restrict__ AA, const float* __restrict__ BBm,
    const float* __restrict__ Aout, float* __restrict__ D)
{
  int l = threadIdx.x;
  int q = l >> 4, c = l & 15;
  int p = blockIdx.x;
  int t0 = p * RIC_S;
  int tw = t0 - RIC_W; if (tw < 0) tw = 0;
  int tend = t0 + RIC_S - 1;
  int row = l >> 2, cb = (l & 3) * 4;   // for 4-consecutive-element global<->LDS staging

  __shared__ float bbs[16 * 20];  // stride 20: 16B-aligned rows, <=2-way bank aliasing (free)
  __shared__ float dis[16 * 20];
  __shared__ float ys[16 * 20];

  // seed: M = Aout[tw] + I staged in dis; D = M M^T + 1e-6 I (exact at tw==0)
  {
    float4 v = *(const float4*)(Aout + (size_t)tw * 256 + l * 4);
    float va[4] = {v.x, v.y, v.z, v.w};
#pragma unroll
    for (int e = 0; e < 4; ++e) if (row == cb + e) va[e] += 1.f;
    *(float4*)&dis[row * 20 + cb] = *(float4*)va;
  }
  __syncthreads();
  float dr[4];
  {
    float a0 = 0, a1 = 0, a2 = 0, a3 = 0;
#pragma unroll
    for (int kb = 0; kb < 4; ++kb) {
      float4 bc4 = *(const float4*)&dis[c * 20 + kb * 4];
      float4 r0 = *(const float4*)&dis[(q * 4 + 0) * 20 + kb * 4];
      float4 r1 = *(const float4*)&dis[(q * 4 + 1) * 20 + kb * 4];
      float4 r2 = *(const float4*)&dis[(q * 4 + 2) * 20 + kb * 4];
      float4 r3 = *(const float4*)&dis[(q * 4 + 3) * 20 + kb * 4];
      a0 += DOT4(r0, bc4); a1 += DOT4(r1, bc4); a2 += DOT4(r2, bc4); a3 += DOT4(r3, bc4);
    }
    dr[0] = a0 + (q * 4 + 0 == c ? 1e-6f : 0.f);
    dr[1] = a1 + (q * 4 + 1 == c ? 1e-6f : 0.f);
    dr[2] = a2 + (q * 4 + 2 == c ? 1e-6f : 0.f);
    dr[3] = a3 + (q * 4 + 3 == c ? 1e-6f : 0.f);
  }

  for (int t = tw; ; ++t) {
    if (t >= t0) {
#pragma unroll
      for (int u = 0; u < 4; ++u)
        D[(size_t)t * 256 + (q * 4 + u) * 16 + c] = dr[u];
    }
    if (t == tend) break;
    float4 bb4 = *(const float4*)(BBm + (size_t)t * 256 + l * 4);
    float aar[4];
#pragma unroll
    for (int u = 0; u < 4; ++u)
      aar[u] = AA[(size_t)(t + 1) * 256 + (q * 4 + u) * 16 + c];

    // ---- Gauss-Jordan inverse of SPD d, all in registers via shuffles ----
#pragma unroll
    for (int k = 0; k < 16; ++k) {
      const int kq = k >> 2, ku = k & 3;
      float rowv = __shfl(dr[ku], (kq << 4) | c);        // d[k][c]
      float pv   = __shfl(dr[ku], (kq << 4) | k);        // d[k][k]
      float cv0  = __shfl(dr[0], (l & 48) | k);          // d[4q+0][k]
      float cv1  = __shfl(dr[1], (l & 48) | k);
      float cv2  = __shfl(dr[2], (l & 48) | k);
      float cv3  = __shfl(dr[3], (l & 48) | k);
      float rpv  = __builtin_amdgcn_rcpf(pv);
      float t1v  = rowv * rpv;
      float cva[4] = {cv0, cv1, cv2, cv3};
#pragma unroll
      for (int u = 0; u < 4; ++u) {
        bool irow = (q == kq) && (u == ku);
        float nv = irow ? ((c == k) ? rpv : t1v)
                        : ((c == k) ? (-cva[u] * rpv) : fmaf(-cva[u], t1v, dr[u]));
        dr[u] = nv;
      }
    }

    __syncthreads();   // prior iteration's LDS reads complete before overwrite
    *(float4*)&bbs[row * 20 + cb] = bb4;
#pragma unroll
    for (int u = 0; u < 4; ++u) dis[(q * 4 + u) * 20 + c] = dr[u];
    __syncthreads();

    // y[i][c] = sum_k Dinv[i][k] * bb[c][k]
    float y0 = 0, y1 = 0, y2 = 0, y3 = 0;
#pragma unroll
    for (int kb = 0; kb < 4; ++kb) {
      float4 bc4 = *(const float4*)&bbs[c * 20 + kb * 4];
      float4 r0 = *(const float4*)&dis[(q * 4 + 0) * 20 + kb * 4];
      float4 r1 = *(const float4*)&dis[(q * 4 + 1) * 20 + kb * 4];
      float4 r2 = *(const float4*)&dis[(q * 4 + 2) * 20 + kb * 4];
      float4 r3 = *(const float4*)&dis[(q * 4 + 3) * 20 + kb * 4];
      y0 += DOT4(r0, bc4); y1 += DOT4(r1, bc4); y2 += DOT4(r2, bc4); y3 += DOT4(r3, bc4);
    }
    ys[(q * 4 + 0) * 20 + c] = y0;
    ys[(q * 4 + 1) * 20 + c] = y1;
    ys[(q * 4 + 2) * 20 + c] = y2;
    ys[(q * 4 + 3) * 20 + c] = y3;
    __syncthreads();

    // d'[i][c] = aa[i][c] - sum_k bb[i][k] * y[k][c]
    float s0 = aar[0], s1 = aar[1], s2 = aar[2], s3 = aar[3];
#pragma unroll
    for (int kb = 0; kb < 4; ++kb) {
      float4 b0 = *(const float4*)&bbs[(q * 4 + 0) * 20 + kb * 4];
      float4 b1 = *(const float4*)&bbs[(q * 4 + 1) * 20 + kb * 4];
      float4 b2 = *(const float4*)&bbs[(q * 4 + 2) * 20 + kb * 4];
      float4 b3 = *(const float4*)&bbs[(q * 4 + 3) * 20 + kb * 4];
      float yk0 = ys[(kb * 4 + 0) * 20 + c];
      float yk1 = ys[(kb * 4 + 1) * 20 + c];
      float yk2 = ys[(kb * 4 + 2) * 20 + c];
      float yk3 = ys[(kb * 4 + 3) * 20 + c];
      s0 -= b0.x * yk0 + b0.y * yk1 + b0.z * yk2 + b0.w * yk3;
      s1 -= b1.x * yk0 + b1.y * yk1 + b1.z * yk2 + b1.w * yk3;
      s2 -= b2.x * yk0 + b2.y * yk1 + b2.z * yk2 + b2.w * yk3;
      s3 -= b3.x * yk0 + b3.y * yk1 + b3.z * yk2 + b3.w * yk3;
    }
    dr[0] = s0; dr[1] = s1; dr[2] = s2; dr[3] = s3;
  }
}

// ---------------- K5: per-t chol, Linv, C (fully parallel) ----------------
__global__ __launch_bounds__(256) void chol_inv(
    const float* __restrict__ D, const float* __restrict__ BBm,
    float* __restrict__ Linv, float* __restrict__ Cmat)
{
  int t = blockIdx.x;
  int tid = threadIdx.x;
  int i = tid >> 4, j = tid & 15;
  __shared__ float d[16][17], li[16][17], rhs[16][17], bb[16][17];
  d[i][j] = D[(size_t)t * 256 + tid];
  bool has_b = (t < T_STEPS - 1);
  if (has_b) bb[i][j] = BBm[(size_t)t * 256 + tid];
  rhs[i][j] = (i == j) ? 1.f : 0.f;
  __syncthreads();
  for (int k = 0; k < 16; ++k) {
    if (tid == k * 16 + k) d[k][k] = sqrtf(d[k][k]);
    __syncthreads();
    if (j == k && i > k) d[i][k] /= d[k][k];
    __syncthreads();
    if (i > k && j > k && j <= i) d[i][j] -= d[i][k] * d[j][k];
    __syncthreads();
  }
  for (int k = 0; k < 16; ++k) {
    if (i == k) li[k][j] = rhs[k][j] / d[k][k];
    __syncthreads();
    if (i > k) rhs[i][j] -= d[i][k] * li[k][j];
    __syncthreads();
  }
  Linv[(size_t)t * 256 + tid] = li[i][j];
  if (has_b) {
    float s = 0.f;
#pragma unroll
    for (int k = 0; k < 16; ++k) s += bb[i][k] * li[j][k];   // C = BB Linv^T
    Cmat[(size_t)t * 256 + tid] = s;
  }
}

// ---------------- K6: wave-level x recursion + epilogue ----------------
#define XS 32
#define XW 192
#define XNCH (T_STEPS / XS)   // 256

__global__ __launch_bounds__(64) void xseq_wave(
    const float* __restrict__ Linv, const float* __restrict__ Cmat,
    const float* __restrict__ mu, const float* __restrict__ eps,
    float* __restrict__ out, float* __restrict__ logdet)
{
  int l = threadIdx.x;
  int q = l >> 4, c = l & 15;
  int p = blockIdx.x;
  int t0 = p * XS;
  int ts = t0 - XW; if (ts < 0) ts = 0;  // ts==0 path exact (no x_{-1})
  int row = l >> 2, cb = (l & 3) * 4;
  __shared__ float lis[16 * 20], cs[16 * 20];
  float xr[4] = {0.f, 0.f, 0.f, 0.f};   // x[4q+u][c]
  float logacc = 0.f;

  for (int t = ts; t < t0 + XS; ++t) {
    float4 li4 = *(const float4*)(Linv + (size_t)t * 256 + l * 4);
    float4 c4 = {0.f, 0.f, 0.f, 0.f};
    if (t > 0) c4 = *(const float4*)(Cmat + (size_t)(t - 1) * 256 + l * 4);
    __syncthreads();
    *(float4*)&lis[row * 20 + cb] = li4;
    *(float4*)&cs[row * 20 + cb] = c4;
    __syncthreads();

    // tmp[i][c] = (i==c) - sum_k C[i][k] x[k][c]
    float tr[4];
    tr[0] = (q * 4 + 0 == c) ? 1.f : 0.f;
    tr[1] = (q * 4 + 1 == c) ? 1.f : 0.f;
    tr[2] = (q * 4 + 2 == c) ? 1.f : 0.f;
    tr[3] = (q * 4 + 3 == c) ? 1.f : 0.f;
    if (t > 0) {
#pragma unroll
      for (int kb = 0; kb < 4; ++kb) {
        float4 r0 = *(const float4*)&cs[(q * 4 + 0) * 20 + kb * 4];
        float4 r1 = *(const float4*)&cs[(q * 4 + 1) * 20 + kb * 4];
        float4 r2 = *(const float4*)&cs[(q * 4 + 2) * 20 + kb * 4];
        float4 r3 = *(const float4*)&cs[(q * 4 + 3) * 20 + kb * 4];
        float a0[4] = {r0.x, r0.y, r0.z, r0.w};
        float a1[4] = {r1.x, r1.y, r1.z, r1.w};
        float a2[4] = {r2.x, r2.y, r2.z, r2.w};
        float a3[4] = {r3.x, r3.y, r3.z, r3.w};
#pragma unroll
        for (int e = 0; e < 4; ++e) {
          float xk = __shfl(xr[e], (kb << 4) | c);   // x[4kb+e][c]
          tr[0] = fmaf(-a0[e], xk, tr[0]);
          tr[1] = fmaf(-a1[e], xk, tr[1]);
          tr[2] = fmaf(-a2[e], xk, tr[2]);
          tr[3] = fmaf(-a3[e], xk, tr[3]);
        }
      }
    }
    // x_new[i][c] = sum_k Linv[i][k] tmp[k][c]
    float x0 = 0, x1 = 0, x2 = 0, x3 = 0;
#pragma unroll
    for (int kb = 0; kb < 4; ++kb) {
      float4 r0 = *(const float4*)&lis[(q * 4 + 0) * 20 + kb * 4];
      float4 r1 = *(const float4*)&lis[(q * 4 + 1) * 20 + kb * 4];
      float4 r2 = *(const float4*)&lis[(q * 4 + 2) * 20 + kb * 4];
      float4 r3 = *(const float4*)&lis[(q * 4 + 3) * 20 + kb * 4];
      float a0[4] = {r0.x, r0.y, r0.z, r0.w};
      float a1[4] = {r1.x, r1.y, r1.z, r1.w};
      float a2[4] = {r2.x, r2.y, r2.z, r2.w};
      float a3[4] = {r3.x, r3.y, r3.z, r3.w};
#pragma unroll
      for (int e = 0; e < 4; ++e) {
        float tk = __shfl(tr[e], (kb << 4) | c);     // tmp[4kb+e][c]
        x0 = fmaf(a0[e], tk, x0);
        x1 = fmaf(a1[e], tk, x1);
        x2 = fmaf(a2[e], tk, x2);
        x3 = fmaf(a3[e], tk, x3);
      }
    }
    xr[0] = x0; xr[1] = x1; xr[2] = x2; xr[3] = x3;

    if (t >= t0) {
      float r0v = fmaxf(x0, 1e-5f), r1v = fmaxf(x1, 1e-5f);
      float r2v = fmaxf(x2, 1e-5f), r3v = fmaxf(x3, 1e-5f);
      if (q == (c >> 2)) {   // this lane holds diagonal element r[c][c] at u=c&3
        int sel = c & 3;
        float dv = sel == 0 ? r0v : (sel == 1 ? r1v : (sel == 2 ? r2v : r3v));
        logacc -= logf(dv);
      }
      float e0 = eps[(size_t)t * 16 + q * 4 + 0];
      float e1 = eps[(size_t)t * 16 + q * 4 + 1];
      float e2 = eps[(size_t)t * 16 + q * 4 + 2];
      float e3 = eps[(size_t)t * 16 + q * 4 + 3];
      float part = r0v * e0 + r1v * e1 + r2v * e2 + r3v * e3;  // partial of sum_k r[k][c]*eps[k]
      part += __shfl_xor(part, 16);
      part += __shfl_xor(part, 32);
      if (q == 0) out[1 + (size_t)t * 16 + c] = mu[(size_t)t * 16 + c] + part;
    }
  }
#pragma unroll
  for (int off = 1; off < 64; off <<= 1) logacc += __shfl_xor(logacc, off);
  if (l == 0) atomicAdd(logdet, logacc);
}

// ---------------- K7: entropy ----------------
__global__ void finalize_entropy(const float* __restrict__ logdet, float* __restrict__ out)
{
  if (threadIdx.x == 0 && blockIdx.x == 0) {
    const double ENT = 0.5 * 1024.0 * 8192.0 * (1.0 + 1.8378770664093454);
    out[0] = (float)(ENT + (double)(*logdet));
  }
}

extern "C" void kernel_launch(void* const* d_in, const int* in_sizes, int n_in,
                              void* d_out, int out_size, void* d_ws, size_t ws_size,
                              hipStream_t stream)
{
  const float* X   = (const float*)d_in[0];
  const float* W1  = (const float*)d_in[1];
  const float* b1  = (const float*)d_in[2];
  const float* Wmu = (const float*)d_in[3];
  const float* bmu = (const float*)d_in[4];
  const float* WA  = (const float*)d_in[5];
  const float* bA  = (const float*)d_in[6];
  const float* WB  = (const float*)d_in[7];
  const float* bB  = (const float*)d_in[8];
  const float* eps = (const float*)d_in[9];
  float* out = (float*)d_out;
  float* ws  = (float*)d_ws;

  // workspace layout (floats), region reuse once producers are dead:
  // [0 .. 8388608)           h      (dead after K2) -> AA@0, BB@2097152, logdet@4194304
  // [8388608 .. 8519680)     mu
  // [8519680 .. 10616832)    Aout   (alive through K4 seed) -> Cmat (K5 output)
  // [10616832 .. 12713984)   Qtop   (dead after K3) -> D
  // [12713984 .. 14811136)   Qbot   (dead after K3) -> Linv
  float* h      = ws;
  float* AAp    = ws;
  float* BBp    = ws + 2097152;
  float* logdet = ws + 4194304;
  float* muw    = ws + 8388608;
  float* Aout   = ws + 8519680;  float* Cmat = Aout;
  float* Qtop   = ws + 10616832; float* Dws  = Qtop;
  float* Qbot   = ws + 12713984; float* Linv = Qbot;

  dim3 blk(256);

  gemm_bias_act<<<dim3(DXX / BN, T_STEPS / BM), blk, 0, stream>>>(X, W1, b1, h, T_STEPS, DXX, DXX, 1);
  gemm_bias_act<<<dim3(1, T_STEPS / BM), blk, 0, stream>>>(h, Wmu, bmu, muw, T_STEPS, 16, DXX, 0);
  gemm_bias_act<<<dim3(256 / BN, T_STEPS / BM), blk, 0, stream>>>(h, WA, bA, Aout, T_STEPS, 256, DXX, 0);
  gemm_bias_act<<<dim3(256 / BN, T_STEPS / BM), blk, 0, stream>>>(h, WB, nullptr, Qtop, T_STEPS, 256, DXX, 0);
  gemm_bias_act<<<dim3(256 / BN, T_STEPS / BM), blk, 0, stream>>>(h, WB + 1024 * 256, nullptr, Qbot, T_STEPS, 256, DXX, 0);
  make_psd<<<dim3(T_STEPS), blk, 0, stream>>>(Aout, Qtop, Qbot, bB, AAp, BBp, logdet);
  riccati_wave<<<dim3(RIC_NCH), dim3(64), 0, stream>>>(AAp, BBp, Aout, Dws);
  chol_inv<<<dim3(T_STEPS), blk, 0, stream>>>(Dws, BBp, Linv, Cmat);
  xseq_wave<<<dim3(XNCH), dim3(64), 0, stream>>>(Linv, Cmat, muw, eps, out, logdet);
  finalize_entropy<<<dim3(1), dim3(64), 0, stream>>>(logdet, out);
}

// Round 6
// 1081.564 us; speedup vs baseline: 2.4760x; 1.2895x over previous
//
#include <hip/hip_runtime.h>
#include <math.h>

// SequentialVAE on MI355X.
// NOTE (R5 post-mortem): the "closed-form D_t = A A^T + eps I" telescoping is
// WRONG — the eps-correction propagates as E' = G(eps+E)G^T with G = B A^{-1},
// and ||G||~2-3 > 1 here, so E inflates to an O(1) stationary process (bounded
// by B B^T). The warmup Riccati recursion is irreducible. This round = R3's
// proven sequential pipeline + bf16 MFMA GEMMs for the dense phase.
//
//  P0  X -> bf16; transpose->bf16 of W1, WA, WBtop, WBbot
//  K1  MFMA bf16 gemm: h = relu(X@W1+b1) -> bf16
//  K2  MFMA bf16 gemms: Aout = h@WA+bA ; Qtop = h@WBtop ; Qbot = h@WBbot (fp32)
//      + mu = h@Wmu+bmu
//  K3  make_psd: AA_t = A A^T + B_{t-1}B_{t-1}^T + 1e-6 I ; BB_t = B_t A_t^T
//  K4  riccati_wave: 1 wave/chunk, 256 chunks x 32 steps, W=192 warmup,
//      seed D = (Aout+I)(Aout+I)^T + 1e-6 I (exact at t=0; warmup converges to
//      the stationary E regardless). GJ inverse in registers via shuffles.
//  K5  chol_inv per t: L=chol(D), Linv=L^{-1}, C = BB Linv^T
//  K6  xseq_wave: 256 chunks x 32 steps, 192-step warmup (x=0):
//      x_t = Linv_t (I - C_{t-1} x_{t-1}); r=max(x,1e-5); logdet; sample_z
//  K7  entropy = logdet + DX*T/2*(1+log(2pi))

#define T_STEPS 8192
#define DXX 1024

typedef __bf16 bf16x8 __attribute__((ext_vector_type(8)));
typedef float f32x4 __attribute__((ext_vector_type(4)));
typedef unsigned short u16x8 __attribute__((ext_vector_type(8)));
typedef unsigned short u16x4 __attribute__((ext_vector_type(4)));

#define DOT4(r, b) ((r).x*(b).x + (r).y*(b).y + (r).z*(b).z + (r).w*(b).w)

__device__ __forceinline__ unsigned short f2bf(float v) {
  unsigned int u = __float_as_uint(v);
  unsigned int r = (u + 0x7FFFu + ((u >> 16) & 1u)) >> 16;   // RN-even
  return (unsigned short)r;
}
__device__ __forceinline__ float bf2f(unsigned short b) {
  return __uint_as_float(((unsigned int)b) << 16);
}

// ---------------- P0a: elementwise fp32 -> bf16 ----------------
__global__ __launch_bounds__(256) void to_bf16(
    const float* __restrict__ src, unsigned short* __restrict__ dst, int n4)
{
  int idx = blockIdx.x * 256 + threadIdx.x;
  if (idx >= n4) return;
  float4 v = ((const float4*)src)[idx];
  u16x4 h;
  h[0] = f2bf(v.x); h[1] = f2bf(v.y); h[2] = f2bf(v.z); h[3] = f2bf(v.w);
  *(u16x4*)(dst + (size_t)idx * 4) = h;
}

// ---------------- P0b: transpose [K][N] -> [N][K] + bf16 ----------------
__global__ __launch_bounds__(256) void transpose_bf16(
    const float* __restrict__ W, unsigned short* __restrict__ Tt, int K, int N)
{
  __shared__ float tile[32][33];
  int k0 = blockIdx.x * 32, n0 = blockIdx.y * 32;
  int c = threadIdx.x & 31, r = threadIdx.x >> 5;  // r in 0..7
#pragma unroll
  for (int e = 0; e < 4; ++e)
    tile[r + 8 * e][c] = W[(size_t)(k0 + r + 8 * e) * N + n0 + c];
  __syncthreads();
#pragma unroll
  for (int e = 0; e < 4; ++e)
    Tt[(size_t)(n0 + r + 8 * e) * K + k0 + c] = f2bf(tile[c][r + 8 * e]);
}

// ---------------- K1/K2: MFMA bf16 GEMM ----------------
// A row-major [M][K] bf16, B transposed [N][K] bf16. 128x128 tile, 4 waves,
// each wave 64x64 via 4x4 grid of 16x16x32 MFMAs.
// mode 1: out = relu(acc+bias) -> bf16. mode 0: out = acc+bias -> fp32.
#define LDT 40   // LDS row stride in ushorts (80B: 16B aligned; <=2-way bank alias, free)

__global__ __launch_bounds__(256) void gemm_mfma(
    const unsigned short* __restrict__ Abf, const unsigned short* __restrict__ Bbf,
    const float* __restrict__ bias, float* __restrict__ outF,
    unsigned short* __restrict__ outBf, int M, int N, int K, int mode)
{
  __shared__ __align__(16) unsigned short At[128 * LDT];
  __shared__ __align__(16) unsigned short Bt[128 * LDT];
  int tid = threadIdx.x;
  int l = tid & 63;
  int w = tid >> 6;
  int wm = w >> 1, wn = w & 1;
  int lane15 = l & 15, quad = l >> 4;
  int bm = blockIdx.y * 128, bn = blockIdx.x * 128;
  int srow = tid >> 1, shalf = tid & 1;
  const size_t aRowOff = (size_t)(bm + srow) * K;
  const size_t bRowOff = (size_t)(bn + srow) * K;

  f32x4 acc[4][4];
#pragma unroll
  for (int mi = 0; mi < 4; ++mi)
#pragma unroll
    for (int ni = 0; ni < 4; ++ni) acc[mi][ni] = (f32x4){0.f, 0.f, 0.f, 0.f};

  for (int k0 = 0; k0 < K; k0 += 32) {
    u16x8 a0 = *(const u16x8*)(Abf + aRowOff + k0 + shalf * 16);
    u16x8 a1 = *(const u16x8*)(Abf + aRowOff + k0 + shalf * 16 + 8);
    u16x8 b0 = *(const u16x8*)(Bbf + bRowOff + k0 + shalf * 16);
    u16x8 b1 = *(const u16x8*)(Bbf + bRowOff + k0 + shalf * 16 + 8);
    __syncthreads();
    *(u16x8*)&At[srow * LDT + shalf * 16] = a0;
    *(u16x8*)&At[srow * LDT + shalf * 16 + 8] = a1;
    *(u16x8*)&Bt[srow * LDT + shalf * 16] = b0;
    *(u16x8*)&Bt[srow * LDT + shalf * 16 + 8] = b1;
    __syncthreads();
    bf16x8 af[4], bfr[4];
#pragma unroll
    for (int mi = 0; mi < 4; ++mi)
      af[mi] = *(const bf16x8*)&At[(wm * 64 + mi * 16 + lane15) * LDT + quad * 8];
#pragma unroll
    for (int ni = 0; ni < 4; ++ni)
      bfr[ni] = *(const bf16x8*)&Bt[(wn * 64 + ni * 16 + lane15) * LDT + quad * 8];
#pragma unroll
    for (int mi = 0; mi < 4; ++mi)
#pragma unroll
      for (int ni = 0; ni < 4; ++ni)
        acc[mi][ni] = __builtin_amdgcn_mfma_f32_16x16x32_bf16(af[mi], bfr[ni], acc[mi][ni], 0, 0, 0);
  }

#pragma unroll
  for (int mi = 0; mi < 4; ++mi) {
#pragma unroll
    for (int ni = 0; ni < 4; ++ni) {
      int gc = bn + wn * 64 + ni * 16 + lane15;
      float bv = bias ? bias[gc] : 0.f;
#pragma unroll
      for (int r = 0; r < 4; ++r) {
        int gr = bm + wm * 64 + mi * 16 + quad * 4 + r;   // C/D: col=lane&15, row=quad*4+reg
        float v = acc[mi][ni][r] + bv;
        if (mode == 1) {
          outBf[(size_t)gr * N + gc] = f2bf(fmaxf(v, 0.f));
        } else {
          outF[(size_t)gr * N + gc] = v;
        }
      }
    }
  }
}

// ---------------- K2b: mu = h @ Wmu + bmu ----------------
__global__ __launch_bounds__(256) void mu_gemm(
    const unsigned short* __restrict__ hbf, const float* __restrict__ Wmu,
    const float* __restrict__ bmu, float* __restrict__ mu)
{
  int idx = blockIdx.x * 256 + threadIdx.x;
  int t = idx >> 4, j = idx & 15;
  const unsigned short* ph = hbf + (size_t)t * 1024;
  float s = bmu[j];
#pragma unroll 8
  for (int k = 0; k < 1024; ++k)
    s = fmaf(bf2f(ph[k]), Wmu[k * 16 + j], s);
  mu[idx] = s;
}

// ---------------- K3: AA_t, BB_t ----------------
__global__ __launch_bounds__(256) void make_psd(
    const float* __restrict__ Aout, const float* __restrict__ Qtop,
    const float* __restrict__ Qbot, const float* __restrict__ bB,
    float* __restrict__ AA, float* __restrict__ BBm, float* __restrict__ logdet)
{
  int t = blockIdx.x;
  int tid = threadIdx.x;
  int i = tid >> 4, j = tid & 15;
  if (t == 0 && tid == 0) *logdet = 0.f;
  __shared__ float a[16][17], bp[16][17], bq[16][17];
  a[i][j] = Aout[(size_t)t * 256 + tid] + (i == j ? 1.f : 0.f);
  bp[i][j] = (t >= 1) ? (Qtop[(size_t)t * 256 + tid] + Qbot[(size_t)(t - 1) * 256 + tid] + bB[tid]) : 0.f;
  bool has_b = (t < T_STEPS - 1);
  if (has_b) bq[i][j] = Qtop[(size_t)(t + 1) * 256 + tid] + Qbot[(size_t)t * 256 + tid] + bB[tid];
  __syncthreads();
  float s = (i == j) ? 1e-6f : 0.f;
#pragma unroll
  for (int k = 0; k < 16; ++k) s += a[i][k] * a[j][k] + bp[i][k] * bp[j][k];
  AA[(size_t)t * 256 + tid] = s;
  if (has_b) {
    float s2 = 0.f;
#pragma unroll
    for (int k = 0; k < 16; ++k) s2 += bq[i][k] * a[j][k];
    BBm[(size_t)t * 256 + tid] = s2;
  }
}

// ---------------- K4: wave-level chunked Riccati (proven R3 code) ----------------
// Layout: lane l = q*16+c (q=l>>4, c=l&15) holds d[4q+u][c], u=0..3 in dr[u].
#define RIC_S 32
#define RIC_W 192
#define RIC_NCH (T_STEPS / RIC_S)   // 256

__global__ __launch_bounds__(64) void riccati_wave(
    const float* __restrict__ AA, const float* __restrict__ BBm,
    const float* __restrict__ Aout, float* __restrict__ D)
{
  int l = threadIdx.x;
  int q = l >> 4, c = l & 15;
  int p = blockIdx.x;
  int t0 = p * RIC_S;
  int tw = t0 - RIC_W; if (tw < 0) tw = 0;
  int tend = t0 + RIC_S - 1;
  int row = l >> 2, cb = (l & 3) * 4;

  __shared__ float bbs[16 * 20];
  __shared__ float dis[16 * 20];
  __shared__ float ys[16 * 20];

  // seed: M = Aout[tw] + I staged in dis; D = M M^T + 1e-6 I (exact at tw==0)
  {
    float4 v = *(const float4*)(Aout + (size_t)tw * 256 + l * 4);
    float va[4] = {v.x, v.y, v.z, v.w};
#pragma unroll
    for (int e = 0; e < 4; ++e) if (row == cb + e) va[e] += 1.f;
    *(float4*)&dis[row * 20 + cb] = *(float4*)va;
  }
  __syncthreads();
  float dr[4];
  {
    float a0 = 0, a1 = 0, a2 = 0, a3 = 0;
#pragma unroll
    for (int kb = 0; kb < 4; ++kb) {
      float4 bc4 = *(const float4*)&dis[c * 20 + kb * 4];
      float4 r0 = *(const float4*)&dis[(q * 4 + 0) * 20 + kb * 4];
      float4 r1 = *(const float4*)&dis[(q * 4 + 1) * 20 + kb * 4];
      float4 r2 = *(const float4*)&dis[(q * 4 + 2) * 20 + kb * 4];
      float4 r3 = *(const float4*)&dis[(q * 4 + 3) * 20 + kb * 4];
      a0 += DOT4(r0, bc4); a1 += DOT4(r1, bc4); a2 += DOT4(r2, bc4); a3 += DOT4(r3, bc4);
    }
    dr[0] = a0 + (q * 4 + 0 == c ? 1e-6f : 0.f);
    dr[1] = a1 + (q * 4 + 1 == c ? 1e-6f : 0.f);
    dr[2] = a2 + (q * 4 + 2 == c ? 1e-6f : 0.f);
    dr[3] = a3 + (q * 4 + 3 == c ? 1e-6f : 0.f);
  }

  for (int t = tw; ; ++t) {
    if (t >= t0) {
#pragma unroll
      for (int u = 0; u < 4; ++u)
        D[(size_t)t * 256 + (q * 4 + u) * 16 + c] = dr[u];
    }
    if (t == tend) break;
    float4 bb4 = *(const float4*)(BBm + (size_t)t * 256 + l * 4);
    float aar[4];
#pragma unroll
    for (int u = 0; u < 4; ++u)
      aar[u] = AA[(size_t)(t + 1) * 256 + (q * 4 + u) * 16 + c];

    // Gauss-Jordan inverse of SPD d, in registers via shuffles
#pragma unroll
    for (int k = 0; k < 16; ++k) {
      const int kq = k >> 2, ku = k & 3;
      float rowv = __shfl(dr[ku], (kq << 4) | c);        // d[k][c]
      float pv   = __shfl(dr[ku], (kq << 4) | k);        // d[k][k]
      float cv0  = __shfl(dr[0], (l & 48) | k);          // d[4q+0][k]
      float cv1  = __shfl(dr[1], (l & 48) | k);
      float cv2  = __shfl(dr[2], (l & 48) | k);
      float cv3  = __shfl(dr[3], (l & 48) | k);
      float rpv  = __builtin_amdgcn_rcpf(pv);
      float t1v  = rowv * rpv;
      float cva[4] = {cv0, cv1, cv2, cv3};
#pragma unroll
      for (int u = 0; u < 4; ++u) {
        bool irow = (q == kq) && (u == ku);
        float nv = irow ? ((c == k) ? rpv : t1v)
                        : ((c == k) ? (-cva[u] * rpv) : fmaf(-cva[u], t1v, dr[u]));
        dr[u] = nv;
      }
    }

    __syncthreads();
    *(float4*)&bbs[row * 20 + cb] = bb4;
#pragma unroll
    for (int u = 0; u < 4; ++u) dis[(q * 4 + u) * 20 + c] = dr[u];
    __syncthreads();

    // y[i][c] = sum_k Dinv[i][k] * bb[c][k]
    float y0 = 0, y1 = 0, y2 = 0, y3 = 0;
#pragma unroll
    for (int kb = 0; kb < 4; ++kb) {
      float4 bc4 = *(const float4*)&bbs[c * 20 + kb * 4];
      float4 r0 = *(const float4*)&dis[(q * 4 + 0) * 20 + kb * 4];
      float4 r1 = *(const float4*)&dis[(q * 4 + 1) * 20 + kb * 4];
      float4 r2 = *(const float4*)&dis[(q * 4 + 2) * 20 + kb * 4];
      float4 r3 = *(const float4*)&dis[(q * 4 + 3) * 20 + kb * 4];
      y0 += DOT4(r0, bc4); y1 += DOT4(r1, bc4); y2 += DOT4(r2, bc4); y3 += DOT4(r3, bc4);
    }
    ys[(q * 4 + 0) * 20 + c] = y0;
    ys[(q * 4 + 1) * 20 + c] = y1;
    ys[(q * 4 + 2) * 20 + c] = y2;
    ys[(q * 4 + 3) * 20 + c] = y3;
    __syncthreads();

    // d'[i][c] = aa[i][c] - sum_k bb[i][k] * y[k][c]
    float s0 = aar[0], s1 = aar[1], s2 = aar[2], s3 = aar[3];
#pragma unroll
    for (int kb = 0; kb < 4; ++kb) {
      float4 b0 = *(const float4*)&bbs[(q * 4 + 0) * 20 + kb * 4];
      float4 b1 = *(const float4*)&bbs[(q * 4 + 1) * 20 + kb * 4];
      float4 b2 = *(const float4*)&bbs[(q * 4 + 2) * 20 + kb * 4];
      float4 b3 = *(const float4*)&bbs[(q * 4 + 3) * 20 + kb * 4];
      float yk0 = ys[(kb * 4 + 0) * 20 + c];
      float yk1 = ys[(kb * 4 + 1) * 20 + c];
      float yk2 = ys[(kb * 4 + 2) * 20 + c];
      float yk3 = ys[(kb * 4 + 3) * 20 + c];
      s0 -= b0.x * yk0 + b0.y * yk1 + b0.z * yk2 + b0.w * yk3;
      s1 -= b1.x * yk0 + b1.y * yk1 + b1.z * yk2 + b1.w * yk3;
      s2 -= b2.x * yk0 + b2.y * yk1 + b2.z * yk2 + b2.w * yk3;
      s3 -= b3.x * yk0 + b3.y * yk1 + b3.z * yk2 + b3.w * yk3;
    }
    dr[0] = s0; dr[1] = s1; dr[2] = s2; dr[3] = s3;
  }
}

// ---------------- K5: per-t chol, Linv, C (proven R3 code) ----------------
__global__ __launch_bounds__(256) void chol_inv(
    const float* __restrict__ D, const float* __restrict__ BBm,
    float* __restrict__ Linv, float* __restrict__ Cmat)
{
  int t = blockIdx.x;
  int tid = threadIdx.x;
  int i = tid >> 4, j = tid & 15;
  __shared__ float d[16][17], li[16][17], rhs[16][17], bb[16][17];
  d[i][j] = D[(size_t)t * 256 + tid];
  bool has_b = (t < T_STEPS - 1);
  if (has_b) bb[i][j] = BBm[(size_t)t * 256 + tid];
  rhs[i][j] = (i == j) ? 1.f : 0.f;
  __syncthreads();
  for (int k = 0; k < 16; ++k) {
    if (tid == k * 16 + k) d[k][k] = sqrtf(d[k][k]);
    __syncthreads();
    if (j == k && i > k) d[i][k] /= d[k][k];
    __syncthreads();
    if (i > k && j > k && j <= i) d[i][j] -= d[i][k] * d[j][k];
    __syncthreads();
  }
  for (int k = 0; k < 16; ++k) {
    if (i == k) li[k][j] = rhs[k][j] / d[k][k];
    __syncthreads();
    if (i > k) rhs[i][j] -= d[i][k] * li[k][j];
    __syncthreads();
  }
  Linv[(size_t)t * 256 + tid] = li[i][j];
  if (has_b) {
    float s = 0.f;
#pragma unroll
    for (int k = 0; k < 16; ++k) s += bb[i][k] * li[j][k];   // C = BB Linv^T
    Cmat[(size_t)t * 256 + tid] = s;
  }
}

// ---------------- K6: wave-level x recursion + epilogue (proven R3 code) ----------------
#define XS 32
#define XW 192
#define XNCH (T_STEPS / XS)   // 256

__global__ __launch_bounds__(64) void xseq_wave(
    const float* __restrict__ Linv, const float* __restrict__ Cmat,
    const float* __restrict__ mu, const float* __restrict__ eps,
    float* __restrict__ out, float* __restrict__ logdet)
{
  int l = threadIdx.x;
  int q = l >> 4, c = l & 15;
  int p = blockIdx.x;
  int t0 = p * XS;
  int ts = t0 - XW; if (ts < 0) ts = 0;  // ts==0 path exact (no x_{-1})
  int row = l >> 2, cb = (l & 3) * 4;
  __shared__ float lis[16 * 20], cs[16 * 20];
  float xr[4] = {0.f, 0.f, 0.f, 0.f};   // x[4q+u][c]
  float logacc = 0.f;

  for (int t = ts; t < t0 + XS; ++t) {
    float4 li4 = *(const float4*)(Linv + (size_t)t * 256 + l * 4);
    float4 c4 = {0.f, 0.f, 0.f, 0.f};
    if (t > 0) c4 = *(const float4*)(Cmat + (size_t)(t - 1) * 256 + l * 4);
    __syncthreads();
    *(float4*)&lis[row * 20 + cb] = li4;
    *(float4*)&cs[row * 20 + cb] = c4;
    __syncthreads();

    // tmp[i][c] = (i==c) - sum_k C[i][k] x[k][c]
    float tr[4];
    tr[0] = (q * 4 + 0 == c) ? 1.f : 0.f;
    tr[1] = (q * 4 + 1 == c) ? 1.f : 0.f;
    tr[2] = (q * 4 + 2 == c) ? 1.f : 0.f;
    tr[3] = (q * 4 + 3 == c) ? 1.f : 0.f;
    if (t > 0) {
#pragma unroll
      for (int kb = 0; kb < 4; ++kb) {
        float4 r0 = *(const float4*)&cs[(q * 4 + 0) * 20 + kb * 4];
        float4 r1 = *(const float4*)&cs[(q * 4 + 1) * 20 + kb * 4];
        float4 r2 = *(const float4*)&cs[(q * 4 + 2) * 20 + kb * 4];
        float4 r3 = *(const float4*)&cs[(q * 4 + 3) * 20 + kb * 4];
        float a0[4] = {r0.x, r0.y, r0.z, r0.w};
        float a1[4] = {r1.x, r1.y, r1.z, r1.w};
        float a2[4] = {r2.x, r2.y, r2.z, r2.w};
        float a3[4] = {r3.x, r3.y, r3.z, r3.w};
#pragma unroll
        for (int e = 0; e < 4; ++e) {
          float xk = __shfl(xr[e], (kb << 4) | c);   // x[4kb+e][c]
          tr[0] = fmaf(-a0[e], xk, tr[0]);
          tr[1] = fmaf(-a1[e], xk, tr[1]);
          tr[2] = fmaf(-a2[e], xk, tr[2]);
          tr[3] = fmaf(-a3[e], xk, tr[3]);
        }
      }
    }
    // x_new[i][c] = sum_k Linv[i][k] tmp[k][c]
    float x0 = 0, x1 = 0, x2 = 0, x3 = 0;
#pragma unroll
    for (int kb = 0; kb < 4; ++kb) {
      float4 r0 = *(const float4*)&lis[(q * 4 + 0) * 20 + kb * 4];
      float4 r1 = *(const float4*)&lis[(q * 4 + 1) * 20 + kb * 4];
      float4 r2 = *(const float4*)&lis[(q * 4 + 2) * 20 + kb * 4];
      float4 r3 = *(const float4*)&lis[(q * 4 + 3) * 20 + kb * 4];
      float a0[4] = {r0.x, r0.y, r0.z, r0.w};
      float a1[4] = {r1.x, r1.y, r1.z, r1.w};
      float a2[4] = {r2.x, r2.y, r2.z, r2.w};
      float a3[4] = {r3.x, r3.y, r3.z, r3.w};
#pragma unroll
      for (int e = 0; e < 4; ++e) {
        float tk = __shfl(tr[e], (kb << 4) | c);     // tmp[4kb+e][c]
        x0 = fmaf(a0[e], tk, x0);
        x1 = fmaf(a1[e], tk, x1);
        x2 = fmaf(a2[e], tk, x2);
        x3 = fmaf(a3[e], tk, x3);
      }
    }
    xr[0] = x0; xr[1] = x1; xr[2] = x2; xr[3] = x3;

    if (t >= t0) {
      float r0v = fmaxf(x0, 1e-5f), r1v = fmaxf(x1, 1e-5f);
      float r2v = fmaxf(x2, 1e-5f), r3v = fmaxf(x3, 1e-5f);
      if (q == (c >> 2)) {   // lane holding diagonal r[c][c] at u=c&3
        int sel = c & 3;
        float dv = sel == 0 ? r0v : (sel == 1 ? r1v : (sel == 2 ? r2v : r3v));
        logacc -= logf(dv);
      }
      float e0 = eps[(size_t)t * 16 + q * 4 + 0];
      float e1 = eps[(size_t)t * 16 + q * 4 + 1];
      float e2 = eps[(size_t)t * 16 + q * 4 + 2];
      float e3 = eps[(size_t)t * 16 + q * 4 + 3];
      float part = r0v * e0 + r1v * e1 + r2v * e2 + r3v * e3;
      part += __shfl_xor(part, 16);
      part += __shfl_xor(part, 32);
      if (q == 0) out[1 + (size_t)t * 16 + c] = mu[(size_t)t * 16 + c] + part;
    }
  }
#pragma unroll
  for (int off = 1; off < 64; off <<= 1) logacc += __shfl_xor(logacc, off);
  if (l == 0) atomicAdd(logdet, logacc);
}

// ---------------- K7: entropy ----------------
__global__ void finalize_entropy(const float* __restrict__ logdet, float* __restrict__ out)
{
  if (threadIdx.x == 0 && blockIdx.x == 0) {
    const double ENT = 0.5 * 1024.0 * 8192.0 * (1.0 + 1.8378770664093454);
    out[0] = (float)(ENT + (double)(*logdet));
  }
}

extern "C" void kernel_launch(void* const* d_in, const int* in_sizes, int n_in,
                              void* d_out, int out_size, void* d_ws, size_t ws_size,
                              hipStream_t stream)
{
  const float* X   = (const float*)d_in[0];
  const float* W1  = (const float*)d_in[1];
  const float* b1  = (const float*)d_in[2];
  const float* Wmu = (const float*)d_in[3];
  const float* bmu = (const float*)d_in[4];
  const float* WA  = (const float*)d_in[5];
  const float* bA  = (const float*)d_in[6];
  const float* WB  = (const float*)d_in[7];
  const float* bB  = (const float*)d_in[8];
  const float* eps = (const float*)d_in[9];
  float* out = (float*)d_out;
  char* ws  = (char*)d_ws;

  // Workspace (peak 45.6 MB, < 59.2 MB proven-safe). Timeline-audited reuse:
  //  [0,16M)        Xbf        (dead after K1)  -> Aout@0, Qtop@8M      (K2)
  //                                             -> Linv@0, Cmat@8M     (K5; Aout dead
  //                                                after riccati seed, Qtop after K3)
  //  [16M,18M)      W1t        (dead after K1)  -> mu@16M, logdet@16M+512K
  //  [18874368,35651584) hbf   (dead after K2)  -> AA@18874368, BB@27262976 (K3)
  //  [35651584,37224448) WtA/WtBt/WtBb (dead after K2)
  //  [37224448,45613056) Qbot  (dead after K3)  -> D@37224448 (K4)
  unsigned short* Xbf  = (unsigned short*)(ws + 0);
  unsigned short* W1t  = (unsigned short*)(ws + 16777216);
  unsigned short* hbf  = (unsigned short*)(ws + 18874368);
  unsigned short* WtA  = (unsigned short*)(ws + 35651584);
  unsigned short* WtBt = (unsigned short*)(ws + 36175872);
  unsigned short* WtBb = (unsigned short*)(ws + 36700160);
  float* Aout   = (float*)(ws + 0);
  float* Qtop   = (float*)(ws + 8388608);
  float* Linv   = (float*)(ws + 0);
  float* Cmat   = (float*)(ws + 8388608);
  float* muw    = (float*)(ws + 16777216);
  float* logdet = (float*)(ws + 17301504);
  float* AAp    = (float*)(ws + 18874368);
  float* BBp    = (float*)(ws + 27262976);
  float* Qbot   = (float*)(ws + 37224448);
  float* Dws    = (float*)(ws + 37224448);

  dim3 blk(256);

  // P0: bf16 conversions
  to_bf16<<<dim3(8192), blk, 0, stream>>>(X, Xbf, 8192 * 1024 / 4);
  transpose_bf16<<<dim3(32, 32), blk, 0, stream>>>(W1, W1t, 1024, 1024);
  transpose_bf16<<<dim3(32, 8), blk, 0, stream>>>(WA, WtA, 1024, 256);
  transpose_bf16<<<dim3(32, 8), blk, 0, stream>>>(WB, WtBt, 1024, 256);
  transpose_bf16<<<dim3(32, 8), blk, 0, stream>>>(WB + 1024 * 256, WtBb, 1024, 256);
  // K1: h = relu(X@W1+b1) -> bf16
  gemm_mfma<<<dim3(8, 64), blk, 0, stream>>>(Xbf, W1t, b1, nullptr, hbf, 8192, 1024, 1024, 1);
  // K2: Aout, Qtop, Qbot (fp32) + mu
  gemm_mfma<<<dim3(2, 64), blk, 0, stream>>>(hbf, WtA, bA, Aout, nullptr, 8192, 256, 1024, 0);
  gemm_mfma<<<dim3(2, 64), blk, 0, stream>>>(hbf, WtBt, nullptr, Qtop, nullptr, 8192, 256, 1024, 0);
  gemm_mfma<<<dim3(2, 64), blk, 0, stream>>>(hbf, WtBb, nullptr, Qbot, nullptr, 8192, 256, 1024, 0);
  mu_gemm<<<dim3(512), blk, 0, stream>>>(hbf, Wmu, bmu, muw);
  // K3: AA, BB (hbf dead; AA/BB overwrite it)
  make_psd<<<dim3(T_STEPS), blk, 0, stream>>>(Aout, Qtop, Qbot, bB, AAp, BBp, logdet);
  // K4: warmup Riccati (Qbot dead; D overwrites it)
  riccati_wave<<<dim3(RIC_NCH), dim3(64), 0, stream>>>(AAp, BBp, Aout, Dws);
  // K5: chol/Linv/C (Aout & Qtop dead; Linv/Cmat overwrite them)
  chol_inv<<<dim3(T_STEPS), blk, 0, stream>>>(Dws, BBp, Linv, Cmat);
  // K6: x recursion + epilogue
  xseq_wave<<<dim3(XNCH), dim3(64), 0, stream>>>(Linv, Cmat, muw, eps, out, logdet);
  // K7
  finalize_entropy<<<dim3(1), dim3(64), 0, stream>>>(logdet, out);
}

// Round 7
// 698.355 us; speedup vs baseline: 3.8347x; 1.5487x over previous
//
#include <hip/hip_runtime.h>
#include <math.h>

// SequentialVAE on MI355X.
// R6 -> R7: same proven pipeline (bf16 MFMA GEMMs + warmup Riccati + warmup x-scan),
// with shorter serial chains: RIC (W=64, S=16, 512 chunks) and xseq (XW=128).
// Evidence: R2 converged warmup from an O(1)-wrong seed in 48 steps; absmax is
// dominated by bf16 GEMM noise (11.9k), not truncation.
//
//  P0  X -> bf16; transpose->bf16 of W1, WA, WBtop, WBbot
//  K1  MFMA bf16 gemm: h = relu(X@W1+b1) -> bf16
//  K2  MFMA bf16 gemms: Aout = h@WA+bA ; Qtop = h@WBtop ; Qbot = h@WBbot (fp32)
//      + mu = h@Wmu+bmu
//  K3  make_psd: AA_t = A A^T + B_{t-1}B_{t-1}^T + 1e-6 I ; BB_t = B_t A_t^T
//  K4  riccati_wave: 1 wave/chunk, 512 chunks x 16 steps, W=64 warmup,
//      seed D = (Aout+I)(Aout+I)^T + 1e-6 I (exact at t=0)
//  K5  chol_inv per t: L=chol(D), Linv=L^{-1}, C = BB Linv^T
//  K6  xseq_wave: 256 chunks x 32 steps, 128-step warmup (x=0)
//  K7  entropy = logdet + DX*T/2*(1+log(2pi))

#define T_STEPS 8192
#define DXX 1024

typedef __bf16 bf16x8 __attribute__((ext_vector_type(8)));
typedef float f32x4 __attribute__((ext_vector_type(4)));
typedef unsigned short u16x8 __attribute__((ext_vector_type(8)));
typedef unsigned short u16x4 __attribute__((ext_vector_type(4)));

#define DOT4(r, b) ((r).x*(b).x + (r).y*(b).y + (r).z*(b).z + (r).w*(b).w)

__device__ __forceinline__ unsigned short f2bf(float v) {
  unsigned int u = __float_as_uint(v);
  unsigned int r = (u + 0x7FFFu + ((u >> 16) & 1u)) >> 16;   // RN-even
  return (unsigned short)r;
}
__device__ __forceinline__ float bf2f(unsigned short b) {
  return __uint_as_float(((unsigned int)b) << 16);
}

// ---------------- P0a: elementwise fp32 -> bf16 ----------------
__global__ __launch_bounds__(256) void to_bf16(
    const float* __restrict__ src, unsigned short* __restrict__ dst, int n4)
{
  int idx = blockIdx.x * 256 + threadIdx.x;
  if (idx >= n4) return;
  float4 v = ((const float4*)src)[idx];
  u16x4 h;
  h[0] = f2bf(v.x); h[1] = f2bf(v.y); h[2] = f2bf(v.z); h[3] = f2bf(v.w);
  *(u16x4*)(dst + (size_t)idx * 4) = h;
}

// ---------------- P0b: transpose [K][N] -> [N][K] + bf16 ----------------
__global__ __launch_bounds__(256) void transpose_bf16(
    const float* __restrict__ W, unsigned short* __restrict__ Tt, int K, int N)
{
  __shared__ float tile[32][33];
  int k0 = blockIdx.x * 32, n0 = blockIdx.y * 32;
  int c = threadIdx.x & 31, r = threadIdx.x >> 5;  // r in 0..7
#pragma unroll
  for (int e = 0; e < 4; ++e)
    tile[r + 8 * e][c] = W[(size_t)(k0 + r + 8 * e) * N + n0 + c];
  __syncthreads();
#pragma unroll
  for (int e = 0; e < 4; ++e)
    Tt[(size_t)(n0 + r + 8 * e) * K + k0 + c] = f2bf(tile[c][r + 8 * e]);
}

// ---------------- K1/K2: MFMA bf16 GEMM ----------------
// A row-major [M][K] bf16, B transposed [N][K] bf16. 128x128 tile, 4 waves,
// each wave 64x64 via 4x4 grid of 16x16x32 MFMAs.
// mode 1: out = relu(acc+bias) -> bf16. mode 0: out = acc+bias -> fp32.
#define LDT 40   // LDS row stride in ushorts (80B: 16B aligned; <=2-way bank alias, free)

__global__ __launch_bounds__(256) void gemm_mfma(
    const unsigned short* __restrict__ Abf, const unsigned short* __restrict__ Bbf,
    const float* __restrict__ bias, float* __restrict__ outF,
    unsigned short* __restrict__ outBf, int M, int N, int K, int mode)
{
  __shared__ __align__(16) unsigned short At[128 * LDT];
  __shared__ __align__(16) unsigned short Bt[128 * LDT];
  int tid = threadIdx.x;
  int l = tid & 63;
  int w = tid >> 6;
  int wm = w >> 1, wn = w & 1;
  int lane15 = l & 15, quad = l >> 4;
  int bm = blockIdx.y * 128, bn = blockIdx.x * 128;
  int srow = tid >> 1, shalf = tid & 1;
  const size_t aRowOff = (size_t)(bm + srow) * K;
  const size_t bRowOff = (size_t)(bn + srow) * K;

  f32x4 acc[4][4];
#pragma unroll
  for (int mi = 0; mi < 4; ++mi)
#pragma unroll
    for (int ni = 0; ni < 4; ++ni) acc[mi][ni] = (f32x4){0.f, 0.f, 0.f, 0.f};

  for (int k0 = 0; k0 < K; k0 += 32) {
    u16x8 a0 = *(const u16x8*)(Abf + aRowOff + k0 + shalf * 16);
    u16x8 a1 = *(const u16x8*)(Abf + aRowOff + k0 + shalf * 16 + 8);
    u16x8 b0 = *(const u16x8*)(Bbf + bRowOff + k0 + shalf * 16);
    u16x8 b1 = *(const u16x8*)(Bbf + bRowOff + k0 + shalf * 16 + 8);
    __syncthreads();
    *(u16x8*)&At[srow * LDT + shalf * 16] = a0;
    *(u16x8*)&At[srow * LDT + shalf * 16 + 8] = a1;
    *(u16x8*)&Bt[srow * LDT + shalf * 16] = b0;
    *(u16x8*)&Bt[srow * LDT + shalf * 16 + 8] = b1;
    __syncthreads();
    bf16x8 af[4], bfr[4];
#pragma unroll
    for (int mi = 0; mi < 4; ++mi)
      af[mi] = *(const bf16x8*)&At[(wm * 64 + mi * 16 + lane15) * LDT + quad * 8];
#pragma unroll
    for (int ni = 0; ni < 4; ++ni)
      bfr[ni] = *(const bf16x8*)&Bt[(wn * 64 + ni * 16 + lane15) * LDT + quad * 8];
#pragma unroll
    for (int mi = 0; mi < 4; ++mi)
#pragma unroll
      for (int ni = 0; ni < 4; ++ni)
        acc[mi][ni] = __builtin_amdgcn_mfma_f32_16x16x32_bf16(af[mi], bfr[ni], acc[mi][ni], 0, 0, 0);
  }

#pragma unroll
  for (int mi = 0; mi < 4; ++mi) {
#pragma unroll
    for (int ni = 0; ni < 4; ++ni) {
      int gc = bn + wn * 64 + ni * 16 + lane15;
      float bv = bias ? bias[gc] : 0.f;
#pragma unroll
      for (int r = 0; r < 4; ++r) {
        int gr = bm + wm * 64 + mi * 16 + quad * 4 + r;   // C/D: col=lane&15, row=quad*4+reg
        float v = acc[mi][ni][r] + bv;
        if (mode == 1) {
          outBf[(size_t)gr * N + gc] = f2bf(fmaxf(v, 0.f));
        } else {
          outF[(size_t)gr * N + gc] = v;
        }
      }
    }
  }
}

// ---------------- K2b: mu = h @ Wmu + bmu ----------------
__global__ __launch_bounds__(256) void mu_gemm(
    const unsigned short* __restrict__ hbf, const float* __restrict__ Wmu,
    const float* __restrict__ bmu, float* __restrict__ mu)
{
  int idx = blockIdx.x * 256 + threadIdx.x;
  int t = idx >> 4, j = idx & 15;
  const unsigned short* ph = hbf + (size_t)t * 1024;
  float s = bmu[j];
#pragma unroll 8
  for (int k = 0; k < 1024; ++k)
    s = fmaf(bf2f(ph[k]), Wmu[k * 16 + j], s);
  mu[idx] = s;
}

// ---------------- K3: AA_t, BB_t ----------------
__global__ __launch_bounds__(256) void make_psd(
    const float* __restrict__ Aout, const float* __restrict__ Qtop,
    const float* __restrict__ Qbot, const float* __restrict__ bB,
    float* __restrict__ AA, float* __restrict__ BBm, float* __restrict__ logdet)
{
  int t = blockIdx.x;
  int tid = threadIdx.x;
  int i = tid >> 4, j = tid & 15;
  if (t == 0 && tid == 0) *logdet = 0.f;
  __shared__ float a[16][17], bp[16][17], bq[16][17];
  a[i][j] = Aout[(size_t)t * 256 + tid] + (i == j ? 1.f : 0.f);
  bp[i][j] = (t >= 1) ? (Qtop[(size_t)t * 256 + tid] + Qbot[(size_t)(t - 1) * 256 + tid] + bB[tid]) : 0.f;
  bool has_b = (t < T_STEPS - 1);
  if (has_b) bq[i][j] = Qtop[(size_t)(t + 1) * 256 + tid] + Qbot[(size_t)t * 256 + tid] + bB[tid];
  __syncthreads();
  float s = (i == j) ? 1e-6f : 0.f;
#pragma unroll
  for (int k = 0; k < 16; ++k) s += a[i][k] * a[j][k] + bp[i][k] * bp[j][k];
  AA[(size_t)t * 256 + tid] = s;
  if (has_b) {
    float s2 = 0.f;
#pragma unroll
    for (int k = 0; k < 16; ++k) s2 += bq[i][k] * a[j][k];
    BBm[(size_t)t * 256 + tid] = s2;
  }
}

// ---------------- K4: wave-level chunked Riccati ----------------
// Layout: lane l = q*16+c (q=l>>4, c=l&15) holds d[4q+u][c], u=0..3 in dr[u].
#define RIC_S 16
#define RIC_W 64
#define RIC_NCH (T_STEPS / RIC_S)   // 512

__global__ __launch_bounds__(64) void riccati_wave(
    const float* __restrict__ AA, const float* __restrict__ BBm,
    const float* __restrict__ Aout, float* __restrict__ D)
{
  int l = threadIdx.x;
  int q = l >> 4, c = l & 15;
  int p = blockIdx.x;
  int t0 = p * RIC_S;
  int tw = t0 - RIC_W; if (tw < 0) tw = 0;
  int tend = t0 + RIC_S - 1;
  int row = l >> 2, cb = (l & 3) * 4;

  __shared__ float bbs[16 * 20];
  __shared__ float dis[16 * 20];
  __shared__ float ys[16 * 20];

  // seed: M = Aout[tw] + I staged in dis; D = M M^T + 1e-6 I (exact at tw==0)
  {
    float4 v = *(const float4*)(Aout + (size_t)tw * 256 + l * 4);
    float va[4] = {v.x, v.y, v.z, v.w};
#pragma unroll
    for (int e = 0; e < 4; ++e) if (row == cb + e) va[e] += 1.f;
    *(float4*)&dis[row * 20 + cb] = *(float4*)va;
  }
  __syncthreads();
  float dr[4];
  {
    float a0 = 0, a1 = 0, a2 = 0, a3 = 0;
#pragma unroll
    for (int kb = 0; kb < 4; ++kb) {
      float4 bc4 = *(const float4*)&dis[c * 20 + kb * 4];
      float4 r0 = *(const float4*)&dis[(q * 4 + 0) * 20 + kb * 4];
      float4 r1 = *(const float4*)&dis[(q * 4 + 1) * 20 + kb * 4];
      float4 r2 = *(const float4*)&dis[(q * 4 + 2) * 20 + kb * 4];
      float4 r3 = *(const float4*)&dis[(q * 4 + 3) * 20 + kb * 4];
      a0 += DOT4(r0, bc4); a1 += DOT4(r1, bc4); a2 += DOT4(r2, bc4); a3 += DOT4(r3, bc4);
    }
    dr[0] = a0 + (q * 4 + 0 == c ? 1e-6f : 0.f);
    dr[1] = a1 + (q * 4 + 1 == c ? 1e-6f : 0.f);
    dr[2] = a2 + (q * 4 + 2 == c ? 1e-6f : 0.f);
    dr[3] = a3 + (q * 4 + 3 == c ? 1e-6f : 0.f);
  }

  for (int t = tw; ; ++t) {
    if (t >= t0) {
#pragma unroll
      for (int u = 0; u < 4; ++u)
        D[(size_t)t * 256 + (q * 4 + u) * 16 + c] = dr[u];
    }
    if (t == tend) break;
    float4 bb4 = *(const float4*)(BBm + (size_t)t * 256 + l * 4);
    float aar[4];
#pragma unroll
    for (int u = 0; u < 4; ++u)
      aar[u] = AA[(size_t)(t + 1) * 256 + (q * 4 + u) * 16 + c];

    // Gauss-Jordan inverse of SPD d, in registers via shuffles
#pragma unroll
    for (int k = 0; k < 16; ++k) {
      const int kq = k >> 2, ku = k & 3;
      float rowv = __shfl(dr[ku], (kq << 4) | c);        // d[k][c]
      float pv   = __shfl(dr[ku], (kq << 4) | k);        // d[k][k]
      float cv0  = __shfl(dr[0], (l & 48) | k);          // d[4q+0][k]
      float cv1  = __shfl(dr[1], (l & 48) | k);
      float cv2  = __shfl(dr[2], (l & 48) | k);
      float cv3  = __shfl(dr[3], (l & 48) | k);
      float rpv  = __builtin_amdgcn_rcpf(pv);
      float t1v  = rowv * rpv;
      float cva[4] = {cv0, cv1, cv2, cv3};
#pragma unroll
      for (int u = 0; u < 4; ++u) {
        bool irow = (q == kq) && (u == ku);
        float nv = irow ? ((c == k) ? rpv : t1v)
                        : ((c == k) ? (-cva[u] * rpv) : fmaf(-cva[u], t1v, dr[u]));
        dr[u] = nv;
      }
    }

    __syncthreads();
    *(float4*)&bbs[row * 20 + cb] = bb4;
#pragma unroll
    for (int u = 0; u < 4; ++u) dis[(q * 4 + u) * 20 + c] = dr[u];
    __syncthreads();

    // y[i][c] = sum_k Dinv[i][k] * bb[c][k]
    float y0 = 0, y1 = 0, y2 = 0, y3 = 0;
#pragma unroll
    for (int kb = 0; kb < 4; ++kb) {
      float4 bc4 = *(const float4*)&bbs[c * 20 + kb * 4];
      float4 r0 = *(const float4*)&dis[(q * 4 + 0) * 20 + kb * 4];
      float4 r1 = *(const float4*)&dis[(q * 4 + 1) * 20 + kb * 4];
      float4 r2 = *(const float4*)&dis[(q * 4 + 2) * 20 + kb * 4];
      float4 r3 = *(const float4*)&dis[(q * 4 + 3) * 20 + kb * 4];
      y0 += DOT4(r0, bc4); y1 += DOT4(r1, bc4); y2 += DOT4(r2, bc4); y3 += DOT4(r3, bc4);
    }
    ys[(q * 4 + 0) * 20 + c] = y0;
    ys[(q * 4 + 1) * 20 + c] = y1;
    ys[(q * 4 + 2) * 20 + c] = y2;
    ys[(q * 4 + 3) * 20 + c] = y3;
    __syncthreads();

    // d'[i][c] = aa[i][c] - sum_k bb[i][k] * y[k][c]
    float s0 = aar[0], s1 = aar[1], s2 = aar[2], s3 = aar[3];
#pragma unroll
    for (int kb = 0; kb < 4; ++kb) {
      float4 b0 = *(const float4*)&bbs[(q * 4 + 0) * 20 + kb * 4];
      float4 b1 = *(const float4*)&bbs[(q * 4 + 1) * 20 + kb * 4];
      float4 b2 = *(const float4*)&bbs[(q * 4 + 2) * 20 + kb * 4];
      float4 b3 = *(const float4*)&bbs[(q * 4 + 3) * 20 + kb * 4];
      float yk0 = ys[(kb * 4 + 0) * 20 + c];
      float yk1 = ys[(kb * 4 + 1) * 20 + c];
      float yk2 = ys[(kb * 4 + 2) * 20 + c];
      float yk3 = ys[(kb * 4 + 3) * 20 + c];
      s0 -= b0.x * yk0 + b0.y * yk1 + b0.z * yk2 + b0.w * yk3;
      s1 -= b1.x * yk0 + b1.y * yk1 + b1.z * yk2 + b1.w * yk3;
      s2 -= b2.x * yk0 + b2.y * yk1 + b2.z * yk2 + b2.w * yk3;
      s3 -= b3.x * yk0 + b3.y * yk1 + b3.z * yk2 + b3.w * yk3;
    }
    dr[0] = s0; dr[1] = s1; dr[2] = s2; dr[3] = s3;
  }
}

// ---------------- K5: per-t chol, Linv, C ----------------
__global__ __launch_bounds__(256) void chol_inv(
    const float* __restrict__ D, const float* __restrict__ BBm,
    float* __restrict__ Linv, float* __restrict__ Cmat)
{
  int t = blockIdx.x;
  int tid = threadIdx.x;
  int i = tid >> 4, j = tid & 15;
  __shared__ float d[16][17], li[16][17], rhs[16][17], bb[16][17];
  d[i][j] = D[(size_t)t * 256 + tid];
  bool has_b = (t < T_STEPS - 1);
  if (has_b) bb[i][j] = BBm[(size_t)t * 256 + tid];
  rhs[i][j] = (i == j) ? 1.f : 0.f;
  __syncthreads();
  for (int k = 0; k < 16; ++k) {
    if (tid == k * 16 + k) d[k][k] = sqrtf(d[k][k]);
    __syncthreads();
    if (j == k && i > k) d[i][k] /= d[k][k];
    __syncthreads();
    if (i > k && j > k && j <= i) d[i][j] -= d[i][k] * d[j][k];
    __syncthreads();
  }
  for (int k = 0; k < 16; ++k) {
    if (i == k) li[k][j] = rhs[k][j] / d[k][k];
    __syncthreads();
    if (i > k) rhs[i][j] -= d[i][k] * li[k][j];
    __syncthreads();
  }
  Linv[(size_t)t * 256 + tid] = li[i][j];
  if (has_b) {
    float s = 0.f;
#pragma unroll
    for (int k = 0; k < 16; ++k) s += bb[i][k] * li[j][k];   // C = BB Linv^T
    Cmat[(size_t)t * 256 + tid] = s;
  }
}

// ---------------- K6: wave-level x recursion + epilogue ----------------
#define XS 32
#define XW 128
#define XNCH (T_STEPS / XS)   // 256

__global__ __launch_bounds__(64) void xseq_wave(
    const float* __restrict__ Linv, const float* __restrict__ Cmat,
    const float* __restrict__ mu, const float* __restrict__ eps,
    float* __restrict__ out, float* __restrict__ logdet)
{
  int l = threadIdx.x;
  int q = l >> 4, c = l & 15;
  int p = blockIdx.x;
  int t0 = p * XS;
  int ts = t0 - XW; if (ts < 0) ts = 0;  // ts==0 path exact (no x_{-1})
  int row = l >> 2, cb = (l & 3) * 4;
  __shared__ float lis[16 * 20], cs[16 * 20];
  float xr[4] = {0.f, 0.f, 0.f, 0.f};   // x[4q+u][c]
  float logacc = 0.f;

  for (int t = ts; t < t0 + XS; ++t) {
    float4 li4 = *(const float4*)(Linv + (size_t)t * 256 + l * 4);
    float4 c4 = {0.f, 0.f, 0.f, 0.f};
    if (t > 0) c4 = *(const float4*)(Cmat + (size_t)(t - 1) * 256 + l * 4);
    __syncthreads();
    *(float4*)&lis[row * 20 + cb] = li4;
    *(float4*)&cs[row * 20 + cb] = c4;
    __syncthreads();

    // tmp[i][c] = (i==c) - sum_k C[i][k] x[k][c]
    float tr[4];
    tr[0] = (q * 4 + 0 == c) ? 1.f : 0.f;
    tr[1] = (q * 4 + 1 == c) ? 1.f : 0.f;
    tr[2] = (q * 4 + 2 == c) ? 1.f : 0.f;
    tr[3] = (q * 4 + 3 == c) ? 1.f : 0.f;
    if (t > 0) {
#pragma unroll
      for (int kb = 0; kb < 4; ++kb) {
        float4 r0 = *(const float4*)&cs[(q * 4 + 0) * 20 + kb * 4];
        float4 r1 = *(const float4*)&cs[(q * 4 + 1) * 20 + kb * 4];
        float4 r2 = *(const float4*)&cs[(q * 4 + 2) * 20 + kb * 4];
        float4 r3 = *(const float4*)&cs[(q * 4 + 3) * 20 + kb * 4];
        float a0[4] = {r0.x, r0.y, r0.z, r0.w};
        float a1[4] = {r1.x, r1.y, r1.z, r1.w};
        float a2[4] = {r2.x, r2.y, r2.z, r2.w};
        float a3[4] = {r3.x, r3.y, r3.z, r3.w};
#pragma unroll
        for (int e = 0; e < 4; ++e) {
          float xk = __shfl(xr[e], (kb << 4) | c);   // x[4kb+e][c]
          tr[0] = fmaf(-a0[e], xk, tr[0]);
          tr[1] = fmaf(-a1[e], xk, tr[1]);
          tr[2] = fmaf(-a2[e], xk, tr[2]);
          tr[3] = fmaf(-a3[e], xk, tr[3]);
        }
      }
    }
    // x_new[i][c] = sum_k Linv[i][k] tmp[k][c]
    float x0 = 0, x1 = 0, x2 = 0, x3 = 0;
#pragma unroll
    for (int kb = 0; kb < 4; ++kb) {
      float4 r0 = *(const float4*)&lis[(q * 4 + 0) * 20 + kb * 4];
      float4 r1 = *(const float4*)&lis[(q * 4 + 1) * 20 + kb * 4];
      float4 r2 = *(const float4*)&lis[(q * 4 + 2) * 20 + kb * 4];
      float4 r3 = *(const float4*)&lis[(q * 4 + 3) * 20 + kb * 4];
      float a0[4] = {r0.x, r0.y, r0.z, r0.w};
      float a1[4] = {r1.x, r1.y, r1.z, r1.w};
      float a2[4] = {r2.x, r2.y, r2.z, r2.w};
      float a3[4] = {r3.x, r3.y, r3.z, r3.w};
#pragma unroll
      for (int e = 0; e < 4; ++e) {
        float tk = __shfl(tr[e], (kb << 4) | c);     // tmp[4kb+e][c]
        x0 = fmaf(a0[e], tk, x0);
        x1 = fmaf(a1[e], tk, x1);
        x2 = fmaf(a2[e], tk, x2);
        x3 = fmaf(a3[e], tk, x3);
      }
    }
    xr[0] = x0; xr[1] = x1; xr[2] = x2; xr[3] = x3;

    if (t >= t0) {
      float r0v = fmaxf(x0, 1e-5f), r1v = fmaxf(x1, 1e-5f);
      float r2v = fmaxf(x2, 1e-5f), r3v = fmaxf(x3, 1e-5f);
      if (q == (c >> 2)) {   // lane holding diagonal r[c][c] at u=c&3
        int sel = c & 3;
        float dv = sel == 0 ? r0v : (sel == 1 ? r1v : (sel == 2 ? r2v : r3v));
        logacc -= logf(dv);
      }
      float e0 = eps[(size_t)t * 16 + q * 4 + 0];
      float e1 = eps[(size_t)t * 16 + q * 4 + 1];
      float e2 = eps[(size_t)t * 16 + q * 4 + 2];
      float e3 = eps[(size_t)t * 16 + q * 4 + 3];
      float part = r0v * e0 + r1v * e1 + r2v * e2 + r3v * e3;
      part += __shfl_xor(part, 16);
      part += __shfl_xor(part, 32);
      if (q == 0) out[1 + (size_t)t * 16 + c] = mu[(size_t)t * 16 + c] + part;
    }
  }
#pragma unroll
  for (int off = 1; off < 64; off <<= 1) logacc += __shfl_xor(logacc, off);
  if (l == 0) atomicAdd(logdet, logacc);
}

// ---------------- K7: entropy ----------------
__global__ void finalize_entropy(const float* __restrict__ logdet, float* __restrict__ out)
{
  if (threadIdx.x == 0 && blockIdx.x == 0) {
    const double ENT = 0.5 * 1024.0 * 8192.0 * (1.0 + 1.8378770664093454);
    out[0] = (float)(ENT + (double)(*logdet));
  }
}

extern "C" void kernel_launch(void* const* d_in, const int* in_sizes, int n_in,
                              void* d_out, int out_size, void* d_ws, size_t ws_size,
                              hipStream_t stream)
{
  const float* X   = (const float*)d_in[0];
  const float* W1  = (const float*)d_in[1];
  const float* b1  = (const float*)d_in[2];
  const float* Wmu = (const float*)d_in[3];
  const float* bmu = (const float*)d_in[4];
  const float* WA  = (const float*)d_in[5];
  const float* bA  = (const float*)d_in[6];
  const float* WB  = (const float*)d_in[7];
  const float* bB  = (const float*)d_in[8];
  const float* eps = (const float*)d_in[9];
  float* out = (float*)d_out;
  char* ws  = (char*)d_ws;

  // Workspace (peak 45.6 MB, < 59.2 MB proven-safe). Timeline-audited reuse:
  //  [0,16M)        Xbf        (dead after K1)  -> Aout@0, Qtop@8M      (K2)
  //                                             -> Linv@0, Cmat@8M     (K5)
  //  [16M,18M)      W1t        (dead after K1)  -> mu@16M, logdet@16M+512K
  //  [18874368,35651584) hbf   (dead after K2)  -> AA@18874368, BB@27262976 (K3)
  //  [35651584,37224448) WtA/WtBt/WtBb (dead after K2)
  //  [37224448,45613056) Qbot  (dead after K3)  -> D@37224448 (K4)
  unsigned short* Xbf  = (unsigned short*)(ws + 0);
  unsigned short* W1t  = (unsigned short*)(ws + 16777216);
  unsigned short* hbf  = (unsigned short*)(ws + 18874368);
  unsigned short* WtA  = (unsigned short*)(ws + 35651584);
  unsigned short* WtBt = (unsigned short*)(ws + 36175872);
  unsigned short* WtBb = (unsigned short*)(ws + 36700160);
  float* Aout   = (float*)(ws + 0);
  float* Qtop   = (float*)(ws + 8388608);
  float* Linv   = (float*)(ws + 0);
  float* Cmat   = (float*)(ws + 8388608);
  float* muw    = (float*)(ws + 16777216);
  float* logdet = (float*)(ws + 17301504);
  float* AAp    = (float*)(ws + 18874368);
  float* BBp    = (float*)(ws + 27262976);
  float* Qbot   = (float*)(ws + 37224448);
  float* Dws    = (float*)(ws + 37224448);

  dim3 blk(256);

  // P0: bf16 conversions
  to_bf16<<<dim3(8192), blk, 0, stream>>>(X, Xbf, 8192 * 1024 / 4);
  transpose_bf16<<<dim3(32, 32), blk, 0, stream>>>(W1, W1t, 1024, 1024);
  transpose_bf16<<<dim3(32, 8), blk, 0, stream>>>(WA, WtA, 1024, 256);
  transpose_bf16<<<dim3(32, 8), blk, 0, stream>>>(WB, WtBt, 1024, 256);
  transpose_bf16<<<dim3(32, 8), blk, 0, stream>>>(WB + 1024 * 256, WtBb, 1024, 256);
  // K1: h = relu(X@W1+b1) -> bf16
  gemm_mfma<<<dim3(8, 64), blk, 0, stream>>>(Xbf, W1t, b1, nullptr, hbf, 8192, 1024, 1024, 1);
  // K2: Aout, Qtop, Qbot (fp32) + mu
  gemm_mfma<<<dim3(2, 64), blk, 0, stream>>>(hbf, WtA, bA, Aout, nullptr, 8192, 256, 1024, 0);
  gemm_mfma<<<dim3(2, 64), blk, 0, stream>>>(hbf, WtBt, nullptr, Qtop, nullptr, 8192, 256, 1024, 0);
  gemm_mfma<<<dim3(2, 64), blk, 0, stream>>>(hbf, WtBb, nullptr, Qbot, nullptr, 8192, 256, 1024, 0);
  mu_gemm<<<dim3(512), blk, 0, stream>>>(hbf, Wmu, bmu, muw);
  // K3: AA, BB (hbf dead; AA/BB overwrite it)
  make_psd<<<dim3(T_STEPS), blk, 0, stream>>>(Aout, Qtop, Qbot, bB, AAp, BBp, logdet);
  // K4: warmup Riccati (Qbot dead; D overwrites it)
  riccati_wave<<<dim3(RIC_NCH), dim3(64), 0, stream>>>(AAp, BBp, Aout, Dws);
  // K5: chol/Linv/C (Aout & Qtop dead; Linv/Cmat overwrite them)
  chol_inv<<<dim3(T_STEPS), blk, 0, stream>>>(Dws, BBp, Linv, Cmat);
  // K6: x recursion + epilogue
  xseq_wave<<<dim3(XNCH), dim3(64), 0, stream>>>(Linv, Cmat, muw, eps, out, logdet);
  // K7
  finalize_entropy<<<dim3(1), dim3(64), 0, stream>>>(logdet, out);
}